// Round 2
// baseline (392.029 us; speedup 1.0000x reference)
//
#include <hip/hip_runtime.h>
#include <math.h>

#define NB      512
#define NELEC   30
#define NATOMS  10
#define NNEN    40      // en graph nodes: 30 electrons + 10 atoms
#define FEAT    64
#define KRBF    64
#define BLOCK   1024
#define NWAVES  (BLOCK/64)
#define NPEE    435     // unique elec-elec pairs
#define NPEN    300     // unique elec-nuc pairs
#define TILE    32      // feature tile; each block-half owns one tile of features
#define TPAD    33      // tile row stride (+1): lanes hit banks (p+ff)%32, 2-way = free

// ---------------- fused LDS layout (in floats) ----------------
// persistent: xyz[96] | axyz[32] | kee(double)=2 floats @128 (byte 512, 8B-aligned)
// then a union of the ee and en working sets (ee phase completes before en init).
#define OFF_XYZ    0
#define OFF_AXYZ   96
#define OFF_KEE    128
#define OFF_BASE   132

#define EE_H_OFF   OFF_BASE
#define EE_AGG_OFF (EE_H_OFF + NELEC*FEAT)
#define EE_FT_OFF  (EE_AGG_OFF + NELEC*FEAT)
#define EE_END     (EE_FT_OFF + NPEE*TPAD)      // 132 + 18195 = 18327 floats

#define EN_H_OFF   OFF_BASE
#define EN_AGG_OFF (EN_H_OFF + NNEN*FEAT)
#define EN_FT_OFF  (EN_AGG_OFF + NNEN*FEAT)
#define EN_END     (EN_FT_OFF + NPEN*TPAD)      // 132 + 15020 = 15152 floats

#define SM_TOTAL   (EE_END > EN_END ? EE_END : EN_END)   // 18327 fl = 73308 B -> 2 blocks/CU

// triangular pair index base for row i (i<j pairs of 30 electrons)
__device__ __forceinline__ int ee_base(int i) { return 29*i - ((i*(i-1))>>1); }

// ==========================================================================
// Fused ee+en GNN. One block per batch. out[b] = exp(k_ee + k_en).
//
// R1 post-mortem: the allocator pins itself to the 64-VGPR tier regardless
// of launch_bounds/waves_per_eu, so facc[64] per thread spills ~44 floats
// to scratch (WRITE_SIZE 92 MB). Fix: make the working set FIT the
// 64-VGPR tier. half = tid>>9 (wave-uniform) owns a 32-feature tile, so
// each thread holds facc[32]. BLOCK=1024; LDS 73 KB -> 2 blocks/CU ->
// 32 waves/CU (full occupancy). Per-feature FP chains are bit-identical
// to the passing kernel (same op sequence, just executed on another lane).
// ==========================================================================
__global__ __launch_bounds__(BLOCK)
void fused_kernel(const float* __restrict__ pos,
                  const float* __restrict__ atoms,
                  const float* __restrict__ emb_ee,
                  const float* __restrict__ wf_ee,
                  const float* __restrict__ bf_ee,
                  const float* __restrict__ wl_ee,
                  const float* __restrict__ bl_ee,
                  const float* __restrict__ wr_ee,
                  const float* __restrict__ br_ee,
                  const float* __restrict__ emb_en,
                  const float* __restrict__ wf_en,
                  const float* __restrict__ bf_en,
                  const float* __restrict__ wl_en,
                  const float* __restrict__ bl_en,
                  const float* __restrict__ wr_en,
                  const float* __restrict__ br_en,
                  const int*   __restrict__ ee_ty,
                  const int*   __restrict__ en_ty,
                  float*       __restrict__ out)
{
    extern __shared__ float sm[];
    float*  xyz  = sm + OFF_XYZ;     // [96]
    float*  axyz = sm + OFF_AXYZ;    // [32]
    double* keeP = reinterpret_cast<double*>(sm + OFF_KEE);

    const int tid  = threadIdx.x;
    const int b    = blockIdx.x;
    const int lane = tid & 63;
    const int w    = tid >> 6;
    const int half = tid >> 9;       // 0 or 1 — wave-uniform feature-tile owner
    const int q    = tid & 511;      // pair slot within the half

    // ---------------- stage positions + atoms + ee h-init ----------------
    {
        float* hS = sm + EE_H_OFF;
        for (int idx = tid; idx < NELEC*3; idx += BLOCK) xyz[idx] = pos[b*NELEC*3 + idx];
        for (int idx = tid; idx < NATOMS*3; idx += BLOCK) axyz[idx] = atoms[idx];
        for (int idx = tid; idx < NELEC*FEAT; idx += BLOCK) {
            int n = idx >> 6, f = idx & 63;
            hS[idx] = emb_ee[ee_ty[n]*FEAT + f];
        }
    }
    __syncthreads();

    // ======================= elec-elec phase =======================
    {
        float* hS   = sm + EE_H_OFF;    // [30][64]
        float* aggS = sm + EE_AGG_OFF;  // [30][64]
        float* fT   = sm + EE_FT_OFF;   // [435][33]

        // ---- filter GEMM: one pair per lane-slot, 32 feats per half ----
        const int p = (q < NPEE) ? q : (NPEE - 1);
        float facc[TILE];
        {
            int i = 0, rem = p;
            while (rem >= NELEC - 1 - i) { rem -= NELEC - 1 - i; ++i; }
            const int j = i + 1 + rem;
            const float dx = xyz[3*i+0] - xyz[3*j+0];
            const float dy = xyz[3*i+1] - xyz[3*j+1];
            const float dz = xyz[3*i+2] - xyz[3*j+2];
            const float dd = sqrtf(dx*dx + dy*dy + dz*dz);

            const float* bfH = bf_ee + half*TILE;                // wave-uniform
            #pragma unroll
            for (int f = 0; f < TILE; ++f) facc[f] = bfH[f];     // s_load
            #pragma unroll 2
            for (int k = 0; k < KRBF; ++k) {
                const float ck = (float)((double)k * (8.0/63.0));
                const float t  = dd - ck;
                const float rk = expf(-t*t);
                const float* wrow = wf_ee + k*FEAT + half*TILE;  // wave-uniform row
                #pragma unroll
                for (int f = 0; f < TILE; ++f) facc[f] = fmaf(rk, wrow[f], facc[f]);
            }
            #pragma unroll
            for (int f = 0; f < TILE; ++f) facc[f] = tanhf(facc[f]);
        }

        // ---- interaction layers ----
        #pragma unroll
        for (int l = 0; l < 2; ++l) {
            const float* wlL = wl_ee + l*FEAT*FEAT;
            const float* blL = bl_ee + l*FEAT;

            #pragma unroll
            for (int t = 0; t < 2; ++t) {
                __syncthreads();   // protect fT from previous tile's readers
                if (half == t) {   // wave-uniform branch
                    #pragma unroll
                    for (int ff = 0; ff < TILE; ++ff)
                        fT[p*TPAD + ff] = facc[ff];              // static index
                }
                __syncthreads();

                // agg[i][t*32+ff] = sum_{j!=i, j asc} h[j][f] * filt[p(i,j)][f]
                // 30*32 = 960 items -> single pass with 1024 threads
                if (tid < NELEC*TILE) {
                    const int i  = tid >> 5;
                    const int ff = tid & 31;
                    const int f  = t*TILE + ff;
                    float a = 0.f;
                    #pragma unroll
                    for (int j = 0; j < NELEC; ++j) {
                        if (j != i) {
                            int pp = (j < i) ? (ee_base(j) + (i - j - 1))
                                             : (ee_base(i) + (j - i - 1));
                            a = fmaf(hS[j*FEAT + f], fT[pp*TPAD + ff], a);
                        }
                    }
                    aggS[i*FEAT + f] = a;
                }
            }
            __syncthreads();

            // h += tanh(agg @ wl + bl)   (lane = feature, wave-strided nodes)
            for (int i = w; i < NELEC; i += NWAVES) {
                float a2 = 0.f;
                const float4* arow = reinterpret_cast<const float4*>(aggS + i*FEAT);
                #pragma unroll
                for (int k = 0; k < FEAT/4; ++k) {
                    float4 av = arow[k];                          // broadcast b128
                    a2 = fmaf(av.x, wlL[(4*k+0)*FEAT + lane], a2);
                    a2 = fmaf(av.y, wlL[(4*k+1)*FEAT + lane], a2);
                    a2 = fmaf(av.z, wlL[(4*k+2)*FEAT + lane], a2);
                    a2 = fmaf(av.w, wlL[(4*k+3)*FEAT + lane], a2);
                }
                hS[i*FEAT + lane] += tanhf(a2 + blL[lane]);
            }
            __syncthreads();
        }

        // ---- readout: kee = (sum_n h[n]) . wr + br   (f64 tail) ----
        if (w == 0) {
            float s = 0.f;
            #pragma unroll
            for (int n = 0; n < NELEC; ++n) s += hS[n*FEAT + lane];
            double dv = (double)s * (double)wr_ee[lane];
            #pragma unroll
            for (int o = 32; o > 0; o >>= 1) dv += __shfl_xor(dv, o, 64);
            if (lane == 0) *keeP = dv + (double)br_ee[0];
        }
    }
    __syncthreads();   // hS read by readout / fT regions about to be reused

    // ======================= elec-nuc phase =======================
    {
        float* hS   = sm + EN_H_OFF;    // [40][64]
        float* aggS = sm + EN_AGG_OFF;  // [40][64]
        float* fT   = sm + EN_FT_OFF;   // [300][33]

        for (int idx = tid; idx < NNEN*FEAT; idx += BLOCK) {
            int n = idx >> 6, f = idx & 63;
            hS[idx] = emb_en[en_ty[n]*FEAT + f];
        }
        __syncthreads();

        // ---- filter GEMM: pair q = a*30 + e (atom-major, matches ref ordering) ----
        const int p = (q < NPEN) ? q : (NPEN - 1);
        float facc[TILE];
        {
            const int a = p / NELEC;
            const int e = p - a*NELEC;
            const float dx = xyz[3*e+0] - axyz[3*a+0];
            const float dy = xyz[3*e+1] - axyz[3*a+1];
            const float dz = xyz[3*e+2] - axyz[3*a+2];
            const float dd = sqrtf(dx*dx + dy*dy + dz*dz);

            const float* bfH = bf_en + half*TILE;                // wave-uniform
            #pragma unroll
            for (int f = 0; f < TILE; ++f) facc[f] = bfH[f];
            #pragma unroll 2
            for (int k = 0; k < KRBF; ++k) {
                const float ck = (float)((double)k * (8.0/63.0));
                const float t  = dd - ck;
                const float rk = expf(-t*t);
                const float* wrow = wf_en + k*FEAT + half*TILE;  // wave-uniform row
                #pragma unroll
                for (int f = 0; f < TILE; ++f) facc[f] = fmaf(rk, wrow[f], facc[f]);
            }
            #pragma unroll
            for (int f = 0; f < TILE; ++f) facc[f] = tanhf(facc[f]);
        }

        #pragma unroll
        for (int l = 0; l < 2; ++l) {
            const float* wlL = wl_en + l*FEAT*FEAT;
            const float* blL = bl_en + l*FEAT;

            #pragma unroll
            for (int t = 0; t < 2; ++t) {
                __syncthreads();
                if (half == t) {   // wave-uniform branch
                    #pragma unroll
                    for (int ff = 0; ff < TILE; ++ff)
                        fT[p*TPAD + ff] = facc[ff];              // static index
                }
                __syncthreads();

                // bipartite messages: 40 nodes x 32 feats = 1280 items, 2 passes
                #pragma unroll
                for (int pass = 0; pass < 2; ++pass) {
                    const int idx = tid + pass*BLOCK;
                    if (idx < NNEN*TILE) {
                        const int n  = idx >> 5;
                        const int ff = idx & 31;
                        const int f  = t*TILE + ff;
                        float a = 0.f;
                        if (n < NELEC) {            // electron node: atoms ascending
                            #pragma unroll
                            for (int at = 0; at < NATOMS; ++at)
                                a = fmaf(hS[(NELEC+at)*FEAT + f],
                                         fT[(at*NELEC + n)*TPAD + ff], a);
                        } else {                    // atom node: electrons ascending
                            const int at = n - NELEC;
                            #pragma unroll
                            for (int e2 = 0; e2 < NELEC; ++e2)
                                a = fmaf(hS[e2*FEAT + f],
                                         fT[(at*NELEC + e2)*TPAD + ff], a);
                        }
                        aggS[n*FEAT + f] = a;
                    }
                }
            }
            __syncthreads();

            for (int n = w; n < NNEN; n += NWAVES) {
                float a2 = 0.f;
                const float4* arow = reinterpret_cast<const float4*>(aggS + n*FEAT);
                #pragma unroll
                for (int k = 0; k < FEAT/4; ++k) {
                    float4 av = arow[k];
                    a2 = fmaf(av.x, wlL[(4*k+0)*FEAT + lane], a2);
                    a2 = fmaf(av.y, wlL[(4*k+1)*FEAT + lane], a2);
                    a2 = fmaf(av.z, wlL[(4*k+2)*FEAT + lane], a2);
                    a2 = fmaf(av.w, wlL[(4*k+3)*FEAT + lane], a2);
                }
                hS[n*FEAT + lane] += tanhf(a2 + blL[lane]);
            }
            __syncthreads();
        }

        // ---- readout + combine: out[b] = exp(k_en + br_en + k_ee) ----
        if (w == 0) {
            float s = 0.f;
            #pragma unroll
            for (int n = 0; n < NNEN; ++n) s += hS[n*FEAT + lane];
            double dv = (double)s * (double)wr_en[lane];
            #pragma unroll
            for (int o = 32; o > 0; o >>= 1) dv += __shfl_xor(dv, o, 64);
            if (lane == 0) out[b] = (float)exp(dv + (double)br_en[0] + *keeP);
        }
    }
}

// ==========================================================================
extern "C" void kernel_launch(void* const* d_in, const int* in_sizes, int n_in,
                              void* d_out, int out_size, void* d_ws, size_t ws_size,
                              hipStream_t stream) {
    const float* pos    = (const float*)d_in[0];
    const float* atoms  = (const float*)d_in[1];
    const float* emb_ee = (const float*)d_in[2];
    const float* wf_ee  = (const float*)d_in[3];
    const float* bf_ee  = (const float*)d_in[4];
    const float* wl_ee  = (const float*)d_in[5];
    const float* bl_ee  = (const float*)d_in[6];
    const float* wr_ee  = (const float*)d_in[7];
    const float* br_ee  = (const float*)d_in[8];
    const float* emb_en = (const float*)d_in[9];
    const float* wf_en  = (const float*)d_in[10];
    const float* bf_en  = (const float*)d_in[11];
    const float* wl_en  = (const float*)d_in[12];
    const float* bl_en  = (const float*)d_in[13];
    const float* wr_en  = (const float*)d_in[14];
    const float* br_en  = (const float*)d_in[15];
    const int*   ee_ty  = (const int*)d_in[18];
    const int*   en_ty  = (const int*)d_in[21];

    float* out = (float*)d_out;        // [512]

    (void)hipFuncSetAttribute((const void*)fused_kernel,
            hipFuncAttributeMaxDynamicSharedMemorySize, SM_TOTAL*(int)sizeof(float));

    fused_kernel<<<NB, BLOCK, SM_TOTAL*sizeof(float), stream>>>(
        pos, atoms,
        emb_ee, wf_ee, bf_ee, wl_ee, bl_ee, wr_ee, br_ee,
        emb_en, wf_en, bf_en, wl_en, bl_en, wr_en, br_en,
        ee_ty, en_ty, out);
}

// Round 3
// 221.504 us; speedup vs baseline: 1.7698x; 1.7698x over previous
//
#include <hip/hip_runtime.h>
#include <math.h>

#define NB      512
#define NELEC   30
#define NATOMS  10
#define NNEN    40      // en graph nodes: 30 electrons + 10 atoms
#define FEAT    64
#define KRBF    64
#define BLOCK   1024
#define NWAVES  (BLOCK/64)
#define NPEE    435     // unique elec-elec pairs
#define NPEN    300     // unique elec-nuc pairs
#define TILE    32      // feature tile; each block-half owns one tile of features
#define FPAD    65      // filt row stride (+1): banks (p+f)%32 -> 2-way max = free

// ---------------- fused LDS layout (in floats) ----------------
// persistent: xyz[96] | axyz[32] | kee(double) @128
// hS/aggS sized for the larger (en) graph; filt sized for the larger (ee) edge set.
#define OFF_XYZ    0
#define OFF_AXYZ   96
#define OFF_KEE    128
#define OFF_BASE   132
#define HS_OFF     OFF_BASE                 // [40][64] (ee phase uses first 30 rows)
#define AGG_OFF    (HS_OFF + NNEN*FEAT)     // [40][64]
#define FILT_OFF   (AGG_OFF + NNEN*FEAT)    // [435][65] (en phase uses first 300 rows)
#define SM_TOTAL   (FILT_OFF + NPEE*FPAD)   // 33527 floats = 134108 B -> 1 block/CU (16 waves)

// triangular pair index base for row i (i<j pairs of 30 electrons)
__device__ __forceinline__ int ee_base(int i) { return 29*i - ((i*(i-1))>>1); }

// ==========================================================================
// Fused ee+en GNN. One block per batch. out[b] = exp(k_ee + k_en).
//
// R2 post-mortem: half = tid>>9 made the filter-weight row pointer
// thread-dependent, so the 32 weights/k-step compiled to per-lane vector
// loads; at the 64-VGPR tier that serialized the k-loop on vmcnt
// (VALUBusy 30%, 345 us). Fix: readfirstlane(half*TILE) -> SGPR offset ->
// weight rows are s_load again (SGPR operands, no VGPR pressure).
// Also: full-width filt[435][65] in LDS written once per phase (occupancy
// was 1 block/CU anyway) -> no per-(l,t) fT rewrite, 2 barriers/layer.
// All FP op sequences remain order-identical to the passing kernel.
// ==========================================================================
__global__ __launch_bounds__(BLOCK)
void fused_kernel(const float* __restrict__ pos,
                  const float* __restrict__ atoms,
                  const float* __restrict__ emb_ee,
                  const float* __restrict__ wf_ee,
                  const float* __restrict__ bf_ee,
                  const float* __restrict__ wl_ee,
                  const float* __restrict__ bl_ee,
                  const float* __restrict__ wr_ee,
                  const float* __restrict__ br_ee,
                  const float* __restrict__ emb_en,
                  const float* __restrict__ wf_en,
                  const float* __restrict__ bf_en,
                  const float* __restrict__ wl_en,
                  const float* __restrict__ bl_en,
                  const float* __restrict__ wr_en,
                  const float* __restrict__ br_en,
                  const int*   __restrict__ ee_ty,
                  const int*   __restrict__ en_ty,
                  float*       __restrict__ out)
{
    extern __shared__ float sm[];
    float*  xyz  = sm + OFF_XYZ;     // [96]
    float*  axyz = sm + OFF_AXYZ;    // [32]
    double* keeP = reinterpret_cast<double*>(sm + OFF_KEE);
    float*  hS   = sm + HS_OFF;      // [<=40][64]
    float*  aggS = sm + AGG_OFF;     // [<=40][64]
    float*  filt = sm + FILT_OFF;    // [<=435][65]

    const int tid  = threadIdx.x;
    const int b    = blockIdx.x;
    const int lane = tid & 63;
    const int w    = tid >> 6;
    const int q    = tid & 511;      // pair slot within the block-half
    // wave-uniform feature-tile offset, forced into an SGPR so the filter
    // weight rows are provably uniform -> s_load (this was R2's regression)
    const int uoff = __builtin_amdgcn_readfirstlane((tid >> 9) * TILE);

    // ---------------- stage positions + atoms + ee h-init ----------------
    for (int idx = tid; idx < NELEC*3; idx += BLOCK) xyz[idx] = pos[b*NELEC*3 + idx];
    for (int idx = tid; idx < NATOMS*3; idx += BLOCK) axyz[idx] = atoms[idx];
    for (int idx = tid; idx < NELEC*FEAT; idx += BLOCK) {
        int n = idx >> 6, f = idx & 63;
        hS[idx] = emb_ee[ee_ty[n]*FEAT + f];
    }
    __syncthreads();

    // ======================= elec-elec phase =======================
    {
        // ---- filter GEMM: one pair per lane-slot, 32 feats per half ----
        const int p = (q < NPEE) ? q : (NPEE - 1);
        {
            int i = 0, rem = p;
            while (rem >= NELEC - 1 - i) { rem -= NELEC - 1 - i; ++i; }
            const int j = i + 1 + rem;
            const float dx = xyz[3*i+0] - xyz[3*j+0];
            const float dy = xyz[3*i+1] - xyz[3*j+1];
            const float dz = xyz[3*i+2] - xyz[3*j+2];
            const float dd = sqrtf(dx*dx + dy*dy + dz*dz);

            float facc[TILE];
            const float* bfH = bf_ee + uoff;                 // uniform -> s_load
            #pragma unroll
            for (int f = 0; f < TILE; ++f) facc[f] = bfH[f];
            #pragma unroll 2
            for (int k = 0; k < KRBF; ++k) {
                const float ck = (float)((double)k * (8.0/63.0));
                const float t  = dd - ck;
                const float rk = expf(-t*t);
                const float* wrow = wf_ee + k*FEAT + uoff;   // uniform row -> s_load
                #pragma unroll
                for (int f = 0; f < TILE; ++f) facc[f] = fmaf(rk, wrow[f], facc[f]);
            }
            #pragma unroll
            for (int ff = 0; ff < TILE; ++ff)
                filt[p*FPAD + uoff + ff] = tanhf(facc[ff]);  // dup q>=435 writes same data
        }
        __syncthreads();   // filt + hS ready

        // ---- interaction layers: 2 barriers per layer ----
        #pragma unroll
        for (int l = 0; l < 2; ++l) {
            const float* wlL = wl_ee + l*FEAT*FEAT;
            const float* blL = bl_ee + l*FEAT;

            // agg[i][f] = sum_{j!=i, j asc} h[j][f] * filt[p(i,j)][f]
            // 30*64 = 1920 items -> 2 passes; each wave handles one node row
            #pragma unroll
            for (int pass = 0; pass < 2; ++pass) {
                const int idx = tid + pass*BLOCK;
                if (idx < NELEC*FEAT) {
                    const int i = idx >> 6;
                    const int f = idx & 63;
                    float a = 0.f;
                    #pragma unroll
                    for (int j = 0; j < NELEC; ++j) {
                        if (j != i) {
                            int pp = (j < i) ? (ee_base(j) + (i - j - 1))
                                             : (ee_base(i) + (j - i - 1));
                            a = fmaf(hS[j*FEAT + f], filt[pp*FPAD + f], a);
                        }
                    }
                    aggS[i*FEAT + f] = a;
                }
            }
            __syncthreads();

            // h += tanh(agg @ wl + bl)   (lane = feature, wave-strided nodes)
            for (int i = w; i < NELEC; i += NWAVES) {
                float a2 = 0.f;
                const float4* arow = reinterpret_cast<const float4*>(aggS + i*FEAT);
                #pragma unroll
                for (int k = 0; k < FEAT/4; ++k) {
                    float4 av = arow[k];                      // broadcast b128
                    a2 = fmaf(av.x, wlL[(4*k+0)*FEAT + lane], a2);
                    a2 = fmaf(av.y, wlL[(4*k+1)*FEAT + lane], a2);
                    a2 = fmaf(av.z, wlL[(4*k+2)*FEAT + lane], a2);
                    a2 = fmaf(av.w, wlL[(4*k+3)*FEAT + lane], a2);
                }
                hS[i*FEAT + lane] += tanhf(a2 + blL[lane]);
            }
            __syncthreads();
        }

        // ---- readout: kee = (sum_n h[n]) . wr + br   (f64 tail) ----
        if (w == 0) {
            float s = 0.f;
            #pragma unroll
            for (int n = 0; n < NELEC; ++n) s += hS[n*FEAT + lane];
            double dv = (double)s * (double)wr_ee[lane];
            #pragma unroll
            for (int o = 32; o > 0; o >>= 1) dv += __shfl_xor(dv, o, 64);
            if (lane == 0) *keeP = dv + (double)br_ee[0];
        }
    }
    __syncthreads();   // hS/filt about to be overwritten by en phase

    // ======================= elec-nuc phase =======================
    {
        for (int idx = tid; idx < NNEN*FEAT; idx += BLOCK) {
            int n = idx >> 6, f = idx & 63;
            hS[idx] = emb_en[en_ty[n]*FEAT + f];
        }

        // ---- filter GEMM: pair p = a*30 + e (atom-major, matches ref ordering) ----
        const int p = (q < NPEN) ? q : (NPEN - 1);
        {
            const int a = p / NELEC;
            const int e = p - a*NELEC;
            const float dx = xyz[3*e+0] - axyz[3*a+0];
            const float dy = xyz[3*e+1] - axyz[3*a+1];
            const float dz = xyz[3*e+2] - axyz[3*a+2];
            const float dd = sqrtf(dx*dx + dy*dy + dz*dz);

            float facc[TILE];
            const float* bfH = bf_en + uoff;                 // uniform -> s_load
            #pragma unroll
            for (int f = 0; f < TILE; ++f) facc[f] = bfH[f];
            #pragma unroll 2
            for (int k = 0; k < KRBF; ++k) {
                const float ck = (float)((double)k * (8.0/63.0));
                const float t  = dd - ck;
                const float rk = expf(-t*t);
                const float* wrow = wf_en + k*FEAT + uoff;   // uniform row -> s_load
                #pragma unroll
                for (int f = 0; f < TILE; ++f) facc[f] = fmaf(rk, wrow[f], facc[f]);
            }
            #pragma unroll
            for (int ff = 0; ff < TILE; ++ff)
                filt[p*FPAD + uoff + ff] = tanhf(facc[ff]);
        }
        __syncthreads();

        #pragma unroll
        for (int l = 0; l < 2; ++l) {
            const float* wlL = wl_en + l*FEAT*FEAT;
            const float* blL = bl_en + l*FEAT;

            // bipartite messages: 40 nodes x 64 feats = 2560 items, 3 passes
            #pragma unroll
            for (int pass = 0; pass < 3; ++pass) {
                const int idx = tid + pass*BLOCK;
                if (idx < NNEN*FEAT) {
                    const int n = idx >> 6;
                    const int f = idx & 63;
                    float a = 0.f;
                    if (n < NELEC) {            // electron node: atoms ascending
                        #pragma unroll
                        for (int at = 0; at < NATOMS; ++at)
                            a = fmaf(hS[(NELEC+at)*FEAT + f],
                                     filt[(at*NELEC + n)*FPAD + f], a);
                    } else {                    // atom node: electrons ascending
                        const int at = n - NELEC;
                        #pragma unroll
                        for (int e2 = 0; e2 < NELEC; ++e2)
                            a = fmaf(hS[e2*FEAT + f],
                                     filt[(at*NELEC + e2)*FPAD + f], a);
                    }
                    aggS[n*FEAT + f] = a;
                }
            }
            __syncthreads();

            for (int n = w; n < NNEN; n += NWAVES) {
                float a2 = 0.f;
                const float4* arow = reinterpret_cast<const float4*>(aggS + n*FEAT);
                #pragma unroll
                for (int k = 0; k < FEAT/4; ++k) {
                    float4 av = arow[k];
                    a2 = fmaf(av.x, wlL[(4*k+0)*FEAT + lane], a2);
                    a2 = fmaf(av.y, wlL[(4*k+1)*FEAT + lane], a2);
                    a2 = fmaf(av.z, wlL[(4*k+2)*FEAT + lane], a2);
                    a2 = fmaf(av.w, wlL[(4*k+3)*FEAT + lane], a2);
                }
                hS[n*FEAT + lane] += tanhf(a2 + blL[lane]);
            }
            __syncthreads();
        }

        // ---- readout + combine: out[b] = exp(k_en + br_en + k_ee) ----
        if (w == 0) {
            float s = 0.f;
            #pragma unroll
            for (int n = 0; n < NNEN; ++n) s += hS[n*FEAT + lane];
            double dv = (double)s * (double)wr_en[lane];
            #pragma unroll
            for (int o = 32; o > 0; o >>= 1) dv += __shfl_xor(dv, o, 64);
            if (lane == 0) out[b] = (float)exp(dv + (double)br_en[0] + *keeP);
        }
    }
}

// ==========================================================================
extern "C" void kernel_launch(void* const* d_in, const int* in_sizes, int n_in,
                              void* d_out, int out_size, void* d_ws, size_t ws_size,
                              hipStream_t stream) {
    const float* pos    = (const float*)d_in[0];
    const float* atoms  = (const float*)d_in[1];
    const float* emb_ee = (const float*)d_in[2];
    const float* wf_ee  = (const float*)d_in[3];
    const float* bf_ee  = (const float*)d_in[4];
    const float* wl_ee  = (const float*)d_in[5];
    const float* bl_ee  = (const float*)d_in[6];
    const float* wr_ee  = (const float*)d_in[7];
    const float* br_ee  = (const float*)d_in[8];
    const float* emb_en = (const float*)d_in[9];
    const float* wf_en  = (const float*)d_in[10];
    const float* bf_en  = (const float*)d_in[11];
    const float* wl_en  = (const float*)d_in[12];
    const float* bl_en  = (const float*)d_in[13];
    const float* wr_en  = (const float*)d_in[14];
    const float* br_en  = (const float*)d_in[15];
    const int*   ee_ty  = (const int*)d_in[18];
    const int*   en_ty  = (const int*)d_in[21];

    float* out = (float*)d_out;        // [512]

    (void)hipFuncSetAttribute((const void*)fused_kernel,
            hipFuncAttributeMaxDynamicSharedMemorySize, SM_TOTAL*(int)sizeof(float));

    fused_kernel<<<NB, BLOCK, SM_TOTAL*sizeof(float), stream>>>(
        pos, atoms,
        emb_ee, wf_ee, bf_ee, wl_ee, bl_ee, wr_ee, br_ee,
        emb_en, wf_en, bf_en, wl_en, bl_en, wr_en, br_en,
        ee_ty, en_ty, out);
}

// Round 4
// 215.785 us; speedup vs baseline: 1.8168x; 1.0265x over previous
//
#include <hip/hip_runtime.h>
#include <math.h>

#define NB      512
#define NELEC   30
#define NATOMS  10
#define NNEN    40      // en graph nodes: 30 electrons + 10 atoms
#define FEAT    64
#define KRBF    64
#define BLOCK   1024
#define NWAVES  (BLOCK/64)
#define NPEE    435     // unique elec-elec pairs
#define NPEN    300     // unique elec-nuc pairs
#define TILE    32      // feature tile; each block-half owns one tile of features
#define FPAD    65      // filt row stride (+1): banks (p+f)%32 -> 2-way max = free
#define WROW    64      // per-wave agg scratch row stride (256 B, float4-aligned)

// ---------------- fused LDS layout (in floats) ----------------
// xyz[96] | axyz[32] | kee(double)@128 | h0[40][64] | h1[40][64] |
// wrow[16][64] | filt[435][65]
#define OFF_XYZ    0
#define OFF_AXYZ   96
#define OFF_KEE    128
#define H0_OFF     132
#define H1_OFF     (H0_OFF + NNEN*FEAT)       // 2692
#define WR_OFF     (H1_OFF + NNEN*FEAT)       // 5252 (x4B = 21008, 16B-aligned)
#define FILT_OFF   (WR_OFF + NWAVES*WROW)     // 6276
#define SM_TOTAL   (FILT_OFF + NPEE*FPAD)     // 34551 floats = 138204 B -> 1 block/CU

// triangular pair index base for row i (i<j pairs of 30 electrons)
__device__ __forceinline__ int ee_base(int i) { return 29*i - ((i*(i-1))>>1); }

// ==========================================================================
// One interaction layer, fused per-wave: wave owns node(s), lane = feature.
// Messages accumulate in a register, round-trip through the wave's private
// LDS row (same-wave dependency -> lgkmcnt only, NO barrier), then the
// float4-broadcast dense update writes h_next. hc is read-only during the
// layer (ping-pong), so no inter-wave race; one barrier per layer (caller).
// FP sequences identical to R3: j-ascending message fma chain, k-ascending
// float4 dense chain, h_new = h_old + tanhf(a2 + bl).
// ==========================================================================
__device__ __forceinline__ void ee_layer(const float* __restrict__ hc,
                                         float* __restrict__ hn,
                                         const float* __restrict__ filt,
                                         float* __restrict__ wr,   // this wave's row
                                         const float* __restrict__ wlL,
                                         const float* __restrict__ blL,
                                         int w, int lane)
{
    for (int i = w; i < NELEC; i += NWAVES) {
        float a = 0.f;
        #pragma unroll
        for (int j = 0; j < NELEC; ++j) {
            if (j != i) {   // wave-uniform
                int pp = (j < i) ? (ee_base(j) + (i - j - 1))
                                 : (ee_base(i) + (j - i - 1));
                a = fmaf(hc[j*FEAT + lane], filt[pp*FPAD + lane], a);
            }
        }
        wr[lane] = a;                         // same-wave roundtrip
        float a2 = 0.f;
        const float4* arow = reinterpret_cast<const float4*>(wr);
        #pragma unroll
        for (int k = 0; k < FEAT/4; ++k) {
            float4 av = arow[k];              // uniform -> LDS broadcast
            a2 = fmaf(av.x, wlL[(4*k+0)*FEAT + lane], a2);
            a2 = fmaf(av.y, wlL[(4*k+1)*FEAT + lane], a2);
            a2 = fmaf(av.z, wlL[(4*k+2)*FEAT + lane], a2);
            a2 = fmaf(av.w, wlL[(4*k+3)*FEAT + lane], a2);
        }
        hn[i*FEAT + lane] = hc[i*FEAT + lane] + tanhf(a2 + blL[lane]);
    }
}

__device__ __forceinline__ void en_layer(const float* __restrict__ hc,
                                         float* __restrict__ hn,
                                         const float* __restrict__ filt,
                                         float* __restrict__ wr,
                                         const float* __restrict__ wlL,
                                         const float* __restrict__ blL,
                                         int w, int lane)
{
    for (int n = w; n < NNEN; n += NWAVES) {
        float a = 0.f;
        if (n < NELEC) {            // wave-uniform: electron node, atoms ascending
            #pragma unroll
            for (int at = 0; at < NATOMS; ++at)
                a = fmaf(hc[(NELEC+at)*FEAT + lane],
                         filt[(at*NELEC + n)*FPAD + lane], a);
        } else {                    // atom node: electrons ascending
            const int at = n - NELEC;
            #pragma unroll
            for (int e2 = 0; e2 < NELEC; ++e2)
                a = fmaf(hc[e2*FEAT + lane],
                         filt[(at*NELEC + e2)*FPAD + lane], a);
        }
        wr[lane] = a;
        float a2 = 0.f;
        const float4* arow = reinterpret_cast<const float4*>(wr);
        #pragma unroll
        for (int k = 0; k < FEAT/4; ++k) {
            float4 av = arow[k];
            a2 = fmaf(av.x, wlL[(4*k+0)*FEAT + lane], a2);
            a2 = fmaf(av.y, wlL[(4*k+1)*FEAT + lane], a2);
            a2 = fmaf(av.z, wlL[(4*k+2)*FEAT + lane], a2);
            a2 = fmaf(av.w, wlL[(4*k+3)*FEAT + lane], a2);
        }
        hn[n*FEAT + lane] = hc[n*FEAT + lane] + tanhf(a2 + blL[lane]);
    }
}

// RBF filter for one pair: facc = tanh(bf + sum_k exp(-(dd-ck)^2) * wf[k]),
// 32-feature half per thread, weights via wave-uniform SGPR rows.
// FP sequence identical to R3.
__device__ __forceinline__ void rbf_filter(float dd, const float* __restrict__ wf,
                                           const float* __restrict__ bf,
                                           int uoff, float* __restrict__ dstrow)
{
    float facc[TILE];
    const float* bfH = bf + uoff;                     // uniform -> s_load
    #pragma unroll
    for (int f = 0; f < TILE; ++f) facc[f] = bfH[f];
    #pragma unroll 2
    for (int k = 0; k < KRBF; ++k) {
        const float ck = (float)((double)k * (8.0/63.0));
        const float t  = dd - ck;
        const float rk = expf(-t*t);
        const float* wrow = wf + k*FEAT + uoff;       // uniform row -> s_load
        #pragma unroll
        for (int f = 0; f < TILE; ++f) facc[f] = fmaf(rk, wrow[f], facc[f]);
    }
    #pragma unroll
    for (int ff = 0; ff < TILE; ++ff) dstrow[uoff + ff] = tanhf(facc[ff]);
}

// ==========================================================================
// Fused ee+en GNN. One block per batch. out[b] = exp(k_ee + k_en).
// Segments (7 barriers total):
//  1 stage+h0ee-init | 2 ee-filter (idle-guarded) | 3 ee-l0 (h0->h1) |
//  4 ee-l1 (h1->h0)  | 5 {w0: ee-readout(h0) || en-filter(SIMD-remapped)
//                        || en-h1-init}           | 6 en-l0 (h1->h0) |
//  7 en-l1 (h0->h1)  | final readout (h1)
// ==========================================================================
__global__ __launch_bounds__(BLOCK)
void fused_kernel(const float* __restrict__ pos,
                  const float* __restrict__ atoms,
                  const float* __restrict__ emb_ee,
                  const float* __restrict__ wf_ee,
                  const float* __restrict__ bf_ee,
                  const float* __restrict__ wl_ee,
                  const float* __restrict__ bl_ee,
                  const float* __restrict__ wr_ee,
                  const float* __restrict__ br_ee,
                  const float* __restrict__ emb_en,
                  const float* __restrict__ wf_en,
                  const float* __restrict__ bf_en,
                  const float* __restrict__ wl_en,
                  const float* __restrict__ bl_en,
                  const float* __restrict__ wr_en,
                  const float* __restrict__ br_en,
                  const int*   __restrict__ ee_ty,
                  const int*   __restrict__ en_ty,
                  float*       __restrict__ out)
{
    extern __shared__ float sm[];
    float*  xyz  = sm + OFF_XYZ;     // [96]
    float*  axyz = sm + OFF_AXYZ;    // [32]
    double* keeP = reinterpret_cast<double*>(sm + OFF_KEE);
    float*  h0   = sm + H0_OFF;      // [40][64]
    float*  h1   = sm + H1_OFF;      // [40][64]
    float*  wrS  = sm + WR_OFF;      // [16][64]
    float*  filt = sm + FILT_OFF;    // [435][65]

    const int tid  = threadIdx.x;
    const int b    = blockIdx.x;
    const int lane = tid & 63;
    const int w    = tid >> 6;
    const int q    = tid & 511;      // pair slot within the block-half
    // wave-uniform feature-tile offset in an SGPR (keeps weight rows scalar)
    const int uoff = __builtin_amdgcn_readfirstlane((tid >> 9) * TILE);
    float* wr = wrS + w*WROW;        // this wave's private agg row

    // -------- segment 1: stage positions + atoms + ee h0-init --------
    for (int idx = tid; idx < NELEC*3; idx += BLOCK) xyz[idx] = pos[b*NELEC*3 + idx];
    for (int idx = tid; idx < NATOMS*3; idx += BLOCK) axyz[idx] = atoms[idx];
    for (int idx = tid; idx < NELEC*FEAT; idx += BLOCK) {
        int n = idx >> 6, f = idx & 63;
        h0[idx] = emb_ee[ee_ty[n]*FEAT + f];
    }
    __syncthreads();

    // -------- segment 2: ee filter (idle-guard: waves w/ no pairs skip) ----
    if (q < NPEE) {
        const int p = q;
        int i = 0, rem = p;
        while (rem >= NELEC - 1 - i) { rem -= NELEC - 1 - i; ++i; }
        const int j = i + 1 + rem;
        const float dx = xyz[3*i+0] - xyz[3*j+0];
        const float dy = xyz[3*i+1] - xyz[3*j+1];
        const float dz = xyz[3*i+2] - xyz[3*j+2];
        const float dd = sqrtf(dx*dx + dy*dy + dz*dz);
        rbf_filter(dd, wf_ee, bf_ee, uoff, filt + p*FPAD);
    }
    __syncthreads();

    // -------- segments 3+4: ee interaction layers (1 barrier each) --------
    ee_layer(h0, h1, filt, wr, wl_ee + 0*FEAT*FEAT, bl_ee + 0*FEAT, w, lane);
    __syncthreads();
    ee_layer(h1, h0, filt, wr, wl_ee + 1*FEAT*FEAT, bl_ee + 1*FEAT, w, lane);
    __syncthreads();

    // -------- segment 5: ee readout (w0, reads h0) || en h1-init || en filter
    for (int idx = tid; idx < NNEN*FEAT; idx += BLOCK) {
        int n = idx >> 6, f = idx & 63;
        h1[idx] = emb_en[en_ty[n]*FEAT + f];
    }
    {
        // SIMD-balanced wave remap for the 300-pair filter:
        // half0 active waves {0,1,2,3,4}, half1 {9,10,11,13,14}
        // -> active-wave count per SIMD = {2,3,3,2} (was {4,4,1,1}).
        const int v = w & 7;
        const int blk = (w < 8) ? (v < 5 ? v : -1)
                                : ((v >= 1 && v <= 3) ? v - 1
                                   : (v == 5 || v == 6) ? v - 2 : -1);
        if (blk >= 0) {
            const int p = blk*64 + lane;
            if (p < NPEN) {
                const int a = p / NELEC;
                const int e = p - a*NELEC;
                const float dx = xyz[3*e+0] - axyz[3*a+0];
                const float dy = xyz[3*e+1] - axyz[3*a+1];
                const float dz = xyz[3*e+2] - axyz[3*a+2];
                const float dd = sqrtf(dx*dx + dy*dy + dz*dz);
                rbf_filter(dd, wf_en, bf_en, uoff, filt + p*FPAD);
            }
        }
    }
    if (w == 0) {   // ee readout: kee = (sum_n h0[n]) . wr + br (f64 tail)
        float s = 0.f;
        #pragma unroll
        for (int n = 0; n < NELEC; ++n) s += h0[n*FEAT + lane];
        double dv = (double)s * (double)wr_ee[lane];
        #pragma unroll
        for (int o = 32; o > 0; o >>= 1) dv += __shfl_xor(dv, o, 64);
        if (lane == 0) *keeP = dv + (double)br_ee[0];
    }
    __syncthreads();

    // -------- segments 6+7: en interaction layers --------
    en_layer(h1, h0, filt, wr, wl_en + 0*FEAT*FEAT, bl_en + 0*FEAT, w, lane);
    __syncthreads();
    en_layer(h0, h1, filt, wr, wl_en + 1*FEAT*FEAT, bl_en + 1*FEAT, w, lane);
    __syncthreads();

    // -------- final readout + combine: out[b] = exp(k_en + br_en + k_ee) ----
    if (w == 0) {
        float s = 0.f;
        #pragma unroll
        for (int n = 0; n < NNEN; ++n) s += h1[n*FEAT + lane];
        double dv = (double)s * (double)wr_en[lane];
        #pragma unroll
        for (int o = 32; o > 0; o >>= 1) dv += __shfl_xor(dv, o, 64);
        if (lane == 0) out[b] = (float)exp(dv + (double)br_en[0] + *keeP);
    }
}

// ==========================================================================
extern "C" void kernel_launch(void* const* d_in, const int* in_sizes, int n_in,
                              void* d_out, int out_size, void* d_ws, size_t ws_size,
                              hipStream_t stream) {
    const float* pos    = (const float*)d_in[0];
    const float* atoms  = (const float*)d_in[1];
    const float* emb_ee = (const float*)d_in[2];
    const float* wf_ee  = (const float*)d_in[3];
    const float* bf_ee  = (const float*)d_in[4];
    const float* wl_ee  = (const float*)d_in[5];
    const float* bl_ee  = (const float*)d_in[6];
    const float* wr_ee  = (const float*)d_in[7];
    const float* br_ee  = (const float*)d_in[8];
    const float* emb_en = (const float*)d_in[9];
    const float* wf_en  = (const float*)d_in[10];
    const float* bf_en  = (const float*)d_in[11];
    const float* wl_en  = (const float*)d_in[12];
    const float* bl_en  = (const float*)d_in[13];
    const float* wr_en  = (const float*)d_in[14];
    const float* br_en  = (const float*)d_in[15];
    const int*   ee_ty  = (const int*)d_in[18];
    const int*   en_ty  = (const int*)d_in[21];

    float* out = (float*)d_out;        // [512]

    (void)hipFuncSetAttribute((const void*)fused_kernel,
            hipFuncAttributeMaxDynamicSharedMemorySize, SM_TOTAL*(int)sizeof(float));

    fused_kernel<<<NB, BLOCK, SM_TOTAL*sizeof(float), stream>>>(
        pos, atoms,
        emb_ee, wf_ee, bf_ee, wl_ee, bl_ee, wr_ee, br_ee,
        emb_en, wf_en, bf_en, wl_en, bl_en, wr_en, br_en,
        ee_ty, en_ty, out);
}